// Round 7
// baseline (616.734 us; speedup 1.0000x reference)
//
#include <hip/hip_runtime.h>
#include <hip/hip_bf16.h>

#define NUM_CLUSTERS 50000

typedef __attribute__((ext_vector_type(8))) short bfx8;
typedef __attribute__((ext_vector_type(4))) float f32x4;

// Monotonic unsigned mapping of f32: preserves order, atomicMax-able.
__device__ __forceinline__ unsigned fkey(float f) {
    unsigned b = __float_as_uint(f);
    return b ^ ((b & 0x80000000u) ? 0xFFFFFFFFu : 0x80000000u);
}
__device__ __forceinline__ float funkey(unsigned k) {
    unsigned b = (k & 0x80000000u) ? (k ^ 0x80000000u) : ~k;
    return __uint_as_float(b);
}
__device__ __forceinline__ unsigned short f2bf(float f) {  // RNE
    unsigned u = __float_as_uint(f);
    return (unsigned short)((u + 0x7FFFu + ((u >> 16) & 1u)) >> 16);
}
__device__ __forceinline__ unsigned pk2bf(float a, float b) {  // packed RNE pair
    __hip_bfloat162 h = __float22bfloat162_rn(make_float2(a, b));
    return *(unsigned*)&h;
}

// One-time per-launch weight repack into MFMA B-fragment order (bf16).
// B-frag for mfma_f32_16x16x32_bf16: lane holds B[k0..k0+7][col],
// col = 16*ct + (lane&15), k0 = kb*32 + (lane>>4)*8.
__global__ __launch_bounds__(256) void prep_weights(
    const float* __restrict__ W1, const float* __restrict__ W2,
    unsigned short* __restrict__ w1f, unsigned short* __restrict__ w2f)
{
    int tid = blockIdx.x * 256 + threadIdx.x;
    if (tid < 512) {                       // W1: 4 col-tiles x 2 k-frags
        int frag = tid >> 6, lane = tid & 63;
        int ct = frag >> 1, kb = frag & 1;
        int col = ct * 16 + (lane & 15);
        int k0 = kb * 32 + (lane >> 4) * 8;
        #pragma unroll
        for (int i = 0; i < 8; ++i)
            w1f[(frag * 64 + lane) * 8 + i] = f2bf(W1[(k0 + i) * 64 + col]);
    } else if (tid < 768) {                // W2: 2 col-tiles x 2 k-frags
        int frag = (tid - 512) >> 6, lane = tid & 63;
        int ct = frag >> 1, kb = frag & 1;
        int col = ct * 16 + (lane & 15);
        int k0 = kb * 32 + (lane >> 4) * 8;
        #pragma unroll
        for (int i = 0; i < 8; ++i)
            w2f[(frag * 64 + lane) * 8 + i] = f2bf(W2[(k0 + i) * 32 + col]);
    }
}

// Block = 256 threads = 4 INDEPENDENT waves (no __syncthreads anywhere).
// Wave w owns nodes [blockBase + w*64, +64) as 4 pipelined groups of 16.
// Per group: COALESCED float4 x loads (exact-fetch) -> bf16 -> 2KB LDS tile
// (ping-pong, staged one group ahead); scattered cluster/aggr filter reads
// also prefetched one group ahead (latency hides under compute);
// MFMA GEMM1 -> LN+SiLU (width-16 shuffles) -> h overwrites tile -> MFMA
// GEMM2 -> o overwrites tile -> coalesced nt stores -> filtered atomics.
__global__ __launch_bounds__(256, 5) void mlp_segmax_kernel(
    const float* __restrict__ x, const int* __restrict__ cluster,
    const unsigned short* __restrict__ w1f, const float* __restrict__ b1,
    const float* __restrict__ ln_g, const float* __restrict__ ln_b,
    const unsigned short* __restrict__ w2f, const float* __restrict__ b2,
    float* __restrict__ out, unsigned* __restrict__ aggr, int N)
{
    __shared__ char smem[4 * 4096];        // per wave: 2 ping-pong 2KB tiles
    const int t = threadIdx.x;
    const int lane = t & 63;
    const int w = t >> 6;
    const int l15 = lane & 15;
    const int q = lane >> 4;
    const long long wbase = (long long)blockIdx.x * 256 + w * 64;
    if (wbase >= N) return;                // whole-wave early exit (N % 64 == 0)
    char* cur = smem + w * 4096;
    char* nxt = cur + 2048;

    // weight fragments (lane-indexed, L2-hot, reused across all 4 groups)
    bfx8 W1F[4][2], W2F[2][2];
    #pragma unroll
    for (int ct = 0; ct < 4; ++ct)
        #pragma unroll
        for (int kb = 0; kb < 2; ++kb)
            W1F[ct][kb] = *(const bfx8*)(w1f + ((ct * 2 + kb) * 64 + lane) * 8);
    #pragma unroll
    for (int ct = 0; ct < 2; ++ct)
        #pragma unroll
        for (int kb = 0; kb < 2; ++kb)
            W2F[ct][kb] = *(const bfx8*)(w2f + ((ct * 2 + kb) * 64 + lane) * 8);

    // per-lane column params (col = 16*tt + l15)
    float g4[4], bb4[4], b1c[4];
    #pragma unroll
    for (int tt = 0; tt < 4; ++tt) {
        g4[tt]  = ln_g[16 * tt + l15];
        bb4[tt] = ln_b[16 * tt + l15];
        b1c[tt] = b1[16 * tt + l15];
    }
    float b2c[2] = { b2[l15], b2[16 + l15] };

    // Staging geometry (16-row tile): pass p, lane -> row = p*4 + q,
    // col = l15*4; swizzled granule g = l15>>1, half = l15&1.
    const int srow = q;                    // + p*4 per pass
    const int sphys_base = (l15 >> 1);     // granule before XOR
    const int shalf = (l15 & 1) << 3;

    // ---- Prologue: stage group 0 tile; prefetch group 0 cluster/filter reads
    {
        #pragma unroll
        for (int p = 0; p < 4; ++p) {
            int row = p * 4 + srow;
            float4 v = *(const float4*)(x + (wbase + row) * 64 + l15 * 4);
            int phys = row * 128 + (((sphys_base) ^ (row & 7)) << 4) + shalf;
            *(uint2*)(cur + phys) = make_uint2(pk2bf(v.x, v.y), pk2bf(v.z, v.w));
        }
    }
    int clr[4];
    unsigned olds[8];
    #pragma unroll
    for (int r = 0; r < 4; ++r) clr[r] = cluster[wbase + q * 4 + r];
    #pragma unroll
    for (int c2 = 0; c2 < 2; ++c2)
        #pragma unroll
        for (int r = 0; r < 4; ++r)
            olds[c2 * 4 + r] = aggr[(long long)clr[r] * 32 + c2 * 16 + l15];

    // ---- 4 pipelined groups of 16 nodes
    #pragma unroll 1
    for (int g = 0; g < 4; ++g) {
        const long long gbase = wbase + g * 16;
        const bool more = (g < 3);

        // 1. prefetch next tile to regs + next scattered reads (issue early)
        float4 nxv[4];
        int nclr[4];
        unsigned nolds[8];
        if (more) {
            #pragma unroll
            for (int p = 0; p < 4; ++p) {
                int row = p * 4 + srow;
                nxv[p] = *(const float4*)(x + (gbase + 16 + row) * 64 + l15 * 4);
            }
            #pragma unroll
            for (int r = 0; r < 4; ++r) nclr[r] = cluster[gbase + 16 + q * 4 + r];
            #pragma unroll
            for (int c2 = 0; c2 < 2; ++c2)
                #pragma unroll
                for (int r = 0; r < 4; ++r)
                    nolds[c2 * 4 + r] = aggr[(long long)nclr[r] * 32 + c2 * 16 + l15];
        }

        // 2. A-frags from current tile: lane (q,l15) = row l15, k0 = kb*32+q*8
        const int arsw = l15 & 7;
        bfx8 af[2];
        #pragma unroll
        for (int kb = 0; kb < 2; ++kb)
            af[kb] = *(const bfx8*)(cur + l15 * 128 + (((kb * 4 + q) ^ arsw) << 4));

        // 3. GEMM1
        f32x4 acc[4];
        #pragma unroll
        for (int tt = 0; tt < 4; ++tt) {
            float b = b1c[tt];
            acc[tt] = (f32x4){b, b, b, b};
        }
        #pragma unroll
        for (int kb = 0; kb < 2; ++kb)
            #pragma unroll
            for (int tt = 0; tt < 4; ++tt)
                acc[tt] = __builtin_amdgcn_mfma_f32_16x16x32_bf16(af[kb], W1F[tt][kb], acc[tt], 0, 0, 0);

        // 4. LayerNorm: row q*4+r lives in the 16 lanes of quarter q
        float s[4];
        #pragma unroll
        for (int r = 0; r < 4; ++r)
            s[r] = acc[0][r] + acc[1][r] + acc[2][r] + acc[3][r];
        #pragma unroll
        for (int m = 1; m < 16; m <<= 1)
            #pragma unroll
            for (int r = 0; r < 4; ++r) s[r] += __shfl_xor(s[r], m, 16);
        float mu[4];
        #pragma unroll
        for (int r = 0; r < 4; ++r) mu[r] = s[r] * (1.f / 64.f);
        float vv[4] = {0.f, 0.f, 0.f, 0.f};
        #pragma unroll
        for (int tt = 0; tt < 4; ++tt)
            #pragma unroll
            for (int r = 0; r < 4; ++r) {
                float d = acc[tt][r] - mu[r];
                vv[r] = fmaf(d, d, vv[r]);
            }
        #pragma unroll
        for (int m = 1; m < 16; m <<= 1)
            #pragma unroll
            for (int r = 0; r < 4; ++r) vv[r] += __shfl_xor(vv[r], m, 16);
        float rs[4];
        #pragma unroll
        for (int r = 0; r < 4; ++r) rs[r] = rsqrtf(vv[r] * (1.f / 64.f) + 1e-5f);

        // 5. affine + SiLU, h overwrites current tile (same wave, DS in-order)
        #pragma unroll
        for (int tt = 0; tt < 4; ++tt)
            #pragma unroll
            for (int r = 0; r < 4; ++r) {
                float val = (acc[tt][r] - mu[r]) * rs[r] * g4[tt] + bb4[tt];
                val = val / (1.f + __expf(-val));   // SiLU
                int node = q * 4 + r;               // local row 0..15
                int col = 16 * tt + l15;
                int phys = node * 128 + ((((col >> 3)) ^ (node & 7)) << 4) + ((col & 7) * 2);
                *(unsigned short*)(cur + phys) = f2bf(val);
            }

        // 6. GEMM2
        bfx8 hf[2];
        #pragma unroll
        for (int kb = 0; kb < 2; ++kb)
            hf[kb] = *(const bfx8*)(cur + l15 * 128 + (((kb * 4 + q) ^ arsw) << 4));
        f32x4 oacc[2];
        #pragma unroll
        for (int c2 = 0; c2 < 2; ++c2) {
            float b = b2c[c2];
            oacc[c2] = (f32x4){b, b, b, b};
        }
        #pragma unroll
        for (int kb = 0; kb < 2; ++kb)
            #pragma unroll
            for (int c2 = 0; c2 < 2; ++c2)
                oacc[c2] = __builtin_amdgcn_mfma_f32_16x16x32_bf16(hf[kb], W2F[c2][kb], oacc[c2], 0, 0, 0);

        // 7. o overwrites tile (f32 [16][32]) -> coalesced nt stores
        #pragma unroll
        for (int c2 = 0; c2 < 2; ++c2)
            #pragma unroll
            for (int r = 0; r < 4; ++r) {
                int node = q * 4 + r;
                int byte = (c2 * 16 + l15) * 4;    // 0..127
                int phys = node * 128 + (((byte >> 4) ^ (node & 7)) << 4) + (byte & 15);
                *(float*)(cur + phys) = oacc[c2][r];
            }
        #pragma unroll
        for (int p = 0; p < 2; ++p) {
            int idx2 = p * 64 + lane;              // float4 index in [16][32]
            int row = idx2 >> 3;
            int c = (idx2 & 7) * 4;
            f32x4 v4 = *(const f32x4*)(cur + row * 128 + (((c >> 2) ^ (row & 7)) << 4));
            __builtin_nontemporal_store(v4, (f32x4*)(out + (gbase + row) * 64 + c));
        }

        // 8. filtered segment-max atomics (fire-and-forget).
        // Safe: slot values only grow; prefetched (staler) read <= current,
        // so skipping only when old >= key implies current >= key.
        #pragma unroll
        for (int c2 = 0; c2 < 2; ++c2)
            #pragma unroll
            for (int r = 0; r < 4; ++r) {
                unsigned key = fkey(oacc[c2][r]);
                if (key > olds[c2 * 4 + r])
                    atomicMax(aggr + (long long)clr[r] * 32 + c2 * 16 + l15, key);
            }

        // 9. write-late: stage prefetched tile into other buffer; rotate state
        if (more) {
            #pragma unroll
            for (int p = 0; p < 4; ++p) {
                int row = p * 4 + srow;
                int phys = row * 128 + (((sphys_base) ^ (row & 7)) << 4) + shalf;
                *(uint2*)(nxt + phys) = make_uint2(pk2bf(nxv[p].x, nxv[p].y),
                                                   pk2bf(nxv[p].z, nxv[p].w));
            }
            #pragma unroll
            for (int r = 0; r < 4; ++r) clr[r] = nclr[r];
            #pragma unroll
            for (int i = 0; i < 8; ++i) olds[i] = nolds[i];
            char* tmp = cur; cur = nxt; nxt = tmp;
        }
    }
}

// Gather: thread handles 4 cols -> out[n, 32+4k..] = decode(aggr[cluster[n]])
__global__ __launch_bounds__(256) void gather_kernel(
    const int* __restrict__ cluster, const unsigned* __restrict__ aggr,
    float* __restrict__ out, int N)
{
    long long idx = (long long)blockIdx.x * 256 + threadIdx.x;
    if (idx >= (long long)N * 8) return;
    int n = (int)(idx >> 3);
    int k4 = (int)(idx & 7) * 4;
    int c = cluster[n];
    uint4 a = *(const uint4*)(aggr + (size_t)c * 32 + k4);
    f32x4 o = {funkey(a.x), funkey(a.y), funkey(a.z), funkey(a.w)};
    __builtin_nontemporal_store(o, (f32x4*)(out + (size_t)n * 64 + 32 + k4));
}

extern "C" void kernel_launch(void* const* d_in, const int* in_sizes, int n_in,
                              void* d_out, int out_size, void* d_ws, size_t ws_size,
                              hipStream_t stream) {
    const float* x     = (const float*)d_in[0];
    const int* cluster = (const int*)d_in[1];
    // d_in[2] = batch (unused by the reference output)
    const float* W1    = (const float*)d_in[3];
    const float* b1    = (const float*)d_in[4];
    const float* ln_g  = (const float*)d_in[5];
    const float* ln_b  = (const float*)d_in[6];
    const float* W2    = (const float*)d_in[7];
    const float* b2    = (const float*)d_in[8];
    float* out = (float*)d_out;

    unsigned* aggr = (unsigned*)d_ws;                           // 6.4 MB
    unsigned short* w1f = (unsigned short*)((char*)d_ws + (size_t)NUM_CLUSTERS * 32 * 4);
    unsigned short* w2f = w1f + 8 * 64 * 8;                     // +8 KB, then +4 KB

    int N = in_sizes[0] / 64;

    hipMemsetAsync(aggr, 0, (size_t)NUM_CLUSTERS * 32 * sizeof(unsigned), stream);
    prep_weights<<<3, 256, 0, stream>>>(W1, W2, w1f, w2f);

    int blocks1 = (N + 255) / 256;
    mlp_segmax_kernel<<<blocks1, 256, 0, stream>>>(
        x, cluster, w1f, b1, ln_g, ln_b, w2f, b2, out, aggr, N);

    long long total2 = (long long)N * 8;
    int blocks2 = (int)((total2 + 255) / 256);
    gather_kernel<<<blocks2, 256, 0, stream>>>(cluster, aggr, out, N);
}

// Round 8
// 281.105 us; speedup vs baseline: 2.1940x; 2.1940x over previous
//
#include <hip/hip_runtime.h>
#include <hip/hip_bf16.h>

#define NUM_CLUSTERS 50000

typedef __attribute__((ext_vector_type(8))) short bfx8;
typedef __attribute__((ext_vector_type(4))) float f32x4;

// Monotonic unsigned mapping of f32: preserves order, atomicMax-able.
__device__ __forceinline__ unsigned fkey(float f) {
    unsigned b = __float_as_uint(f);
    return b ^ ((b & 0x80000000u) ? 0xFFFFFFFFu : 0x80000000u);
}
__device__ __forceinline__ float funkey(unsigned k) {
    unsigned b = (k & 0x80000000u) ? (k ^ 0x80000000u) : ~k;
    return __uint_as_float(b);
}
__device__ __forceinline__ unsigned short f2bf(float f) {  // RNE
    unsigned u = __float_as_uint(f);
    return (unsigned short)((u + 0x7FFFu + ((u >> 16) & 1u)) >> 16);
}
__device__ __forceinline__ unsigned pk2bf(float a, float b) {  // packed RNE pair
    __hip_bfloat162 h = __float22bfloat162_rn(make_float2(a, b));
    return *(unsigned*)&h;
}

// One-time per-launch weight repack into MFMA B-fragment order (bf16).
// B-frag for mfma_f32_16x16x32_bf16: lane holds B[k0..k0+7][col],
// col = 16*ct + (lane&15), k0 = kb*32 + (lane>>4)*8.
__global__ __launch_bounds__(256) void prep_weights(
    const float* __restrict__ W1, const float* __restrict__ W2,
    unsigned short* __restrict__ w1f, unsigned short* __restrict__ w2f)
{
    int tid = blockIdx.x * 256 + threadIdx.x;
    if (tid < 512) {                       // W1: 4 col-tiles x 2 k-frags
        int frag = tid >> 6, lane = tid & 63;
        int ct = frag >> 1, kb = frag & 1;
        int col = ct * 16 + (lane & 15);
        int k0 = kb * 32 + (lane >> 4) * 8;
        #pragma unroll
        for (int i = 0; i < 8; ++i)
            w1f[(frag * 64 + lane) * 8 + i] = f2bf(W1[(k0 + i) * 64 + col]);
    } else if (tid < 768) {                // W2: 2 col-tiles x 2 k-frags
        int frag = (tid - 512) >> 6, lane = tid & 63;
        int ct = frag >> 1, kb = frag & 1;
        int col = ct * 16 + (lane & 15);
        int k0 = kb * 32 + (lane >> 4) * 8;
        #pragma unroll
        for (int i = 0; i < 8; ++i)
            w2f[(frag * 64 + lane) * 8 + i] = f2bf(W2[(k0 + i) * 32 + col]);
    }
}

// ROUND-5 ANCHOR STRUCTURE + (a) nt x-loads, (b) hoisted filter reads.
// Block = 256 threads = 4 INDEPENDENT waves (no __syncthreads anywhere).
// Wave w owns nodes [blockBase + w*64, +64) and an 8 KB LDS quadrant.
// Stage x coalesced (nt, streaming) -> bf16 LDS (XOR-swizzled granules);
// per 16-node group: scattered cluster/aggr filter reads FIRST (latency
// hides under compute) -> MFMA GEMM1 -> LN+SiLU (width-16 shuffles) -> h
// back to own rows -> MFMA GEMM2 -> o to the dead rows -> filtered atomics.
// After all groups: wave-local coalesced full-line nt stores of out[:, :32].
__global__ __launch_bounds__(256, 5) void mlp_segmax_kernel(
    const float* __restrict__ x, const int* __restrict__ cluster,
    const unsigned short* __restrict__ w1f, const float* __restrict__ b1,
    const float* __restrict__ ln_g, const float* __restrict__ ln_b,
    const unsigned short* __restrict__ w2f, const float* __restrict__ b2,
    float* __restrict__ out, unsigned* __restrict__ aggr, int N)
{
    __shared__ char smem[256 * 128];       // 4 waves x 8 KB quadrants
    const int t = threadIdx.x;
    const int lane = t & 63;
    const int w = t >> 6;
    const int l15 = lane & 15;
    const int q = lane >> 4;
    const long long wbase = (long long)blockIdx.x * 256 + w * 64;
    if (wbase >= N) return;                // whole-wave early exit (N % 64 == 0)
    char* wmem = smem + w * 8192;

    // ---- Stage: wave-private coalesced x load (nt streaming) -> bf16 LDS
    #pragma unroll 4
    for (int p = 0; p < 16; ++p) {
        int le = (p * 64 + lane) * 4;      // elem 0..4095 within wave tile
        f32x4 v = __builtin_nontemporal_load((const f32x4*)(x + wbase * 64 + le));
        int row = le >> 6;                 // 0..63
        int k = le & 63;
        int g = k >> 3;
        int half = (k >> 2) & 1;
        int phys = row * 128 + ((g ^ (row & 7)) << 4) + (half << 3);
        *(uint2*)(wmem + phys) = make_uint2(pk2bf(v[0], v[1]), pk2bf(v[2], v[3]));
    }

    // weight fragments (lane-indexed, L2-hot, reused across all 4 groups)
    bfx8 W1F[4][2], W2F[2][2];
    #pragma unroll
    for (int ct = 0; ct < 4; ++ct)
        #pragma unroll
        for (int kb = 0; kb < 2; ++kb)
            W1F[ct][kb] = *(const bfx8*)(w1f + ((ct * 2 + kb) * 64 + lane) * 8);
    #pragma unroll
    for (int ct = 0; ct < 2; ++ct)
        #pragma unroll
        for (int kb = 0; kb < 2; ++kb)
            W2F[ct][kb] = *(const bfx8*)(w2f + ((ct * 2 + kb) * 64 + lane) * 8);

    // per-lane column params (col = 16*tt + l15)
    float g4[4], bb4[4], b1c[4];
    #pragma unroll
    for (int tt = 0; tt < 4; ++tt) {
        g4[tt]  = ln_g[16 * tt + l15];
        bb4[tt] = ln_b[16 * tt + l15];
        b1c[tt] = b1[16 * tt + l15];
    }
    float b2c[2] = { b2[l15], b2[16 + l15] };

    // ---- 4 groups of 16 nodes
    #pragma unroll 1
    for (int g = 0; g < 4; ++g) {
        const int base = g * 16;           // local row base
        const int arow = base + l15;
        const int arsw = arow & 7;

        // EARLY scattered filter reads (depend only on cluster[]): their
        // ~900cy latency hides under GEMM1+LN+GEMM2. Safe: slot values only
        // grow within the launch; a stale read <= current, and we skip only
        // when old >= key, which implies current >= key.
        int clr[4];
        #pragma unroll
        for (int r = 0; r < 4; ++r)
            clr[r] = cluster[wbase + base + q * 4 + r];
        unsigned olds[8];
        #pragma unroll
        for (int c2 = 0; c2 < 2; ++c2)
            #pragma unroll
            for (int r = 0; r < 4; ++r)
                olds[c2 * 4 + r] = aggr[(long long)clr[r] * 32 + c2 * 16 + l15];

        // A-frags: lane reads x[arow][k0..k0+7], k0 = kb*32 + q*8
        bfx8 af[2];
        #pragma unroll
        for (int kb = 0; kb < 2; ++kb)
            af[kb] = *(const bfx8*)(wmem + arow * 128 + (((kb * 4 + q) ^ arsw) << 4));

        // GEMM1
        f32x4 acc[4];
        #pragma unroll
        for (int tt = 0; tt < 4; ++tt) {
            float b = b1c[tt];
            acc[tt] = (f32x4){b, b, b, b};
        }
        #pragma unroll
        for (int kb = 0; kb < 2; ++kb)
            #pragma unroll
            for (int tt = 0; tt < 4; ++tt)
                acc[tt] = __builtin_amdgcn_mfma_f32_16x16x32_bf16(af[kb], W1F[tt][kb], acc[tt], 0, 0, 0);

        // LayerNorm: row q*4+r lives in the 16 lanes of quarter q
        float s[4];
        #pragma unroll
        for (int r = 0; r < 4; ++r)
            s[r] = acc[0][r] + acc[1][r] + acc[2][r] + acc[3][r];
        #pragma unroll
        for (int m = 1; m < 16; m <<= 1)
            #pragma unroll
            for (int r = 0; r < 4; ++r) s[r] += __shfl_xor(s[r], m, 16);
        float mu[4];
        #pragma unroll
        for (int r = 0; r < 4; ++r) mu[r] = s[r] * (1.f / 64.f);
        float vv[4] = {0.f, 0.f, 0.f, 0.f};
        #pragma unroll
        for (int tt = 0; tt < 4; ++tt)
            #pragma unroll
            for (int r = 0; r < 4; ++r) {
                float d = acc[tt][r] - mu[r];
                vv[r] = fmaf(d, d, vv[r]);
            }
        #pragma unroll
        for (int m = 1; m < 16; m <<= 1)
            #pragma unroll
            for (int r = 0; r < 4; ++r) vv[r] += __shfl_xor(vv[r], m, 16);
        float rs[4];
        #pragma unroll
        for (int r = 0; r < 4; ++r) rs[r] = rsqrtf(vv[r] * (1.f / 64.f) + 1e-5f);

        // affine + SiLU, pack bf16, write h rows (own wave's rows, DS in-order)
        #pragma unroll
        for (int tt = 0; tt < 4; ++tt)
            #pragma unroll
            for (int r = 0; r < 4; ++r) {
                float val = (acc[tt][r] - mu[r]) * rs[r] * g4[tt] + bb4[tt];
                val = val / (1.f + __expf(-val));   // SiLU
                int node = base + q * 4 + r;
                int col = 16 * tt + l15;
                int phys = node * 128 + ((((col >> 3)) ^ (node & 7)) << 4) + ((col & 7) * 2);
                *(unsigned short*)(wmem + phys) = f2bf(val);
            }

        // GEMM2 A-frags from h (same rows, same wave -> ordered)
        bfx8 hf[2];
        #pragma unroll
        for (int kb = 0; kb < 2; ++kb)
            hf[kb] = *(const bfx8*)(wmem + arow * 128 + (((kb * 4 + q) ^ arsw) << 4));
        f32x4 oacc[2];
        #pragma unroll
        for (int c2 = 0; c2 < 2; ++c2) {
            float b = b2c[c2];
            oacc[c2] = (f32x4){b, b, b, b};
        }
        #pragma unroll
        for (int kb = 0; kb < 2; ++kb)
            #pragma unroll
            for (int c2 = 0; c2 < 2; ++c2)
                oacc[c2] = __builtin_amdgcn_mfma_f32_16x16x32_bf16(hf[kb], W2F[c2][kb], oacc[c2], 0, 0, 0);

        // o -> the group's now-dead LDS rows, f32 [16][32], swizzled granules
        #pragma unroll
        for (int c2 = 0; c2 < 2; ++c2)
            #pragma unroll
            for (int r = 0; r < 4; ++r) {
                int node = base + q * 4 + r;
                int byte = (c2 * 16 + l15) * 4;    // 0..127
                int phys = node * 128 + (((byte >> 4) ^ (node & 7)) << 4) + (byte & 15);
                *(float*)(wmem + phys) = oacc[c2][r];
            }

        // filtered segment-max atomics (fire-and-forget, no return)
        #pragma unroll
        for (int c2 = 0; c2 < 2; ++c2)
            #pragma unroll
            for (int r = 0; r < 4; ++r) {
                unsigned key = fkey(oacc[c2][r]);
                if (key > olds[c2 * 4 + r])
                    atomicMax(aggr + (long long)clr[r] * 32 + c2 * 16 + l15, key);
            }
    }

    // ---- Wave-local coalesced full-line stores of out[:, 0:32] (nt hint)
    #pragma unroll 2
    for (int p = 0; p < 8; ++p) {
        int le = (p * 64 + lane) * 4;      // f32 elem within [64][32] o-tile
        int row = le >> 5;                 // 0..63
        int c = le & 31;                   // multiple of 4
        f32x4 v4 = *(const f32x4*)(wmem + row * 128 + (((c >> 2) ^ (row & 7)) << 4));
        __builtin_nontemporal_store(v4, (f32x4*)(out + (wbase + row) * 64 + c));
    }
}

// Gather: thread handles 4 cols -> out[n, 32+4k..] = decode(aggr[cluster[n]])
__global__ __launch_bounds__(256) void gather_kernel(
    const int* __restrict__ cluster, const unsigned* __restrict__ aggr,
    float* __restrict__ out, int N)
{
    long long idx = (long long)blockIdx.x * 256 + threadIdx.x;
    if (idx >= (long long)N * 8) return;
    int n = (int)(idx >> 3);
    int k4 = (int)(idx & 7) * 4;
    int c = cluster[n];
    uint4 a = *(const uint4*)(aggr + (size_t)c * 32 + k4);
    f32x4 o = {funkey(a.x), funkey(a.y), funkey(a.z), funkey(a.w)};
    __builtin_nontemporal_store(o, (f32x4*)(out + (size_t)n * 64 + 32 + k4));
}

extern "C" void kernel_launch(void* const* d_in, const int* in_sizes, int n_in,
                              void* d_out, int out_size, void* d_ws, size_t ws_size,
                              hipStream_t stream) {
    const float* x     = (const float*)d_in[0];
    const int* cluster = (const int*)d_in[1];
    // d_in[2] = batch (unused by the reference output)
    const float* W1    = (const float*)d_in[3];
    const float* b1    = (const float*)d_in[4];
    const float* ln_g  = (const float*)d_in[5];
    const float* ln_b  = (const float*)d_in[6];
    const float* W2    = (const float*)d_in[7];
    const float* b2    = (const float*)d_in[8];
    float* out = (float*)d_out;

    unsigned* aggr = (unsigned*)d_ws;                           // 6.4 MB
    unsigned short* w1f = (unsigned short*)((char*)d_ws + (size_t)NUM_CLUSTERS * 32 * 4);
    unsigned short* w2f = w1f + 8 * 64 * 8;                     // +8 KB, then +4 KB

    int N = in_sizes[0] / 64;

    hipMemsetAsync(aggr, 0, (size_t)NUM_CLUSTERS * 32 * sizeof(unsigned), stream);
    prep_weights<<<3, 256, 0, stream>>>(W1, W2, w1f, w2f);

    int blocks1 = (N + 255) / 256;
    mlp_segmax_kernel<<<blocks1, 256, 0, stream>>>(
        x, cluster, w1f, b1, ln_g, ln_b, w2f, b2, out, aggr, N);

    long long total2 = (long long)N * 8;
    int blocks2 = (int)((total2 + 255) / 256);
    gather_kernel<<<blocks2, 256, 0, stream>>>(cluster, aggr, out, N);
}